// Round 15
// baseline (201.314 us; speedup 1.0000x reference)
//
#include <hip/hip_runtime.h>

typedef _Float16 half8  __attribute__((ext_vector_type(8)));
typedef _Float16 half4  __attribute__((ext_vector_type(4)));
typedef float    f32x4  __attribute__((ext_vector_type(4)));
typedef unsigned long long u64;

#define B_ 16
#define C_ 256
#define N_ 4096
#define TAU 0.025f

// [n=128][i=256] f16 plane, 16B-chunk XOR swizzle (proven correct R12/R13/R14).
#define XI(n, i) ( ((n) << 8) | ( ( ( ((i) >> 3) ^ ((((n) & 3) << 1) ^ (((n) >> 2) & 7) ^ (((n) >> 5) & 3)) ) & 31 ) << 3 ) | ((i) & 7) )

__device__ __forceinline__ u64 shfl_xor_u64(u64 v, int m) {
    unsigned lo = __shfl_xor((unsigned)v, m);
    unsigned hi = __shfl_xor((unsigned)(v >> 32), m);
    return ((u64)hi << 32) | lo;
}
// merge top-2 B into A (packed keys: higher = better; ~n low 32 gives first-index tie rule)
__device__ __forceinline__ void t2m(u64& A1, u64& A2, u64 B1, u64 B2) {
    bool aw = A1 > B1;
    u64 T1 = aw ? A1 : B1;
    u64 lv = aw ? B1 : A1;
    u64 wv = aw ? A2 : B2;
    A2 = lv > wv ? lv : wv;
    A1 = T1;
}
__device__ __forceinline__ float unkey(unsigned key) {
    unsigned u = (key & 0x80000000u) ? (key ^ 0x80000000u) : ~key;
    return __uint_as_float(u);
}

// ---------- prep: W' = 16*W -> f16 (hi only), A-fragment-major ----------
__global__ void prep_w(const float* __restrict__ W, _Float16* __restrict__ WfH) {
    int t = blockIdx.x * 256 + threadIdx.x;  // 0..8191
    int l = t & 63, g = t >> 6;
    int s = g & 7, cb = g >> 3;
    int c = cb * 16 + (l & 15);
    int i0 = s * 32 + (l >> 4) * 8;
    int base = ((cb * 8 + s) * 64 + l) * 8;
#pragma unroll
    for (int j = 0; j < 8; ++j)
        WfH[base + j] = (_Float16)(16.0f * W[c * C_ + i0 + j]);
}

// ---------- main: k-outer, 128-n window, FULL 256 c per block (x read once) ----------
// grid: 16 b * 32 nw = 512 blocks; 1024 thr = 16 waves; wave w: c[16w,16w+16) x 128 n.
// LDS padded to 83 KB -> 1 block/CU -> 4 waves/SIMD -> VGPR cap 128 -> NO SPILL
// (R12-R14 spilled because 64KB LDS let the compiler target 8 waves/SIMD = 64 VGPRs).
__global__ __launch_bounds__(1024, 4) void vn_main(
    const float* __restrict__ x, const _Float16* __restrict__ WfH,
    ulonglong2* __restrict__ btop)
{
    __shared__ __align__(16) _Float16 X[128 * 256 + 9728];   // 83 KB: occupancy clamp

    const int tid  = threadIdx.x;
    const int lane = tid & 63;
    const int wid  = tid >> 6;          // 0..15 : 16-c slice
    const int b    = blockIdx.x >> 5;
    const int nw   = blockIdx.x & 31;
    const int n0   = nw << 7;
    const int g    = lane >> 4;
    const int t16  = lane & 15;

    const float* xb = x + ((size_t)(b * 768) << 12);

    // stage mapping: sg-group (32 lanes) covers 4 i-rows x 128 n; nl lane = 4 n (f32x4)
    const int nl = tid & 31;
    const int sg = tid >> 5;            // 0..31; round T: i0 = (T*32+sg)*4

#define SLD(VS, T, K) do { int i0_ = (((T) * 32 + sg) << 2);                       \
    _Pragma("unroll") for (int rr = 0; rr < 4; ++rr)                               \
        VS[rr] = *(const f32x4*)(xb + (((i0_ + rr) * 3 + (K)) << 12) + n0 + (nl << 2)); \
    } while (0)

#define SWR(VS, T) do { int i0_ = (((T) * 32 + sg) << 2);                          \
    _Pragma("unroll") for (int j = 0; j < 4; ++j) {                                \
        half4 hh; hh[0] = (_Float16)VS[0][j]; hh[1] = (_Float16)VS[1][j];          \
        hh[2] = (_Float16)VS[2][j]; hh[3] = (_Float16)VS[3][j];                    \
        *(half4*)(&X[XI(4 * nl + j, i0_)]) = hh; }                                 \
    } while (0)

#define WOFF(S) ((((wid << 3) + (S)) * 64 + lane) << 3)

    f32x4 dp[8];
#pragma unroll
    for (int nf = 0; nf < 8; ++nf) dp[nf] = (f32x4){0.f, 0.f, 0.f, 0.f};

    for (int k = 0; k < 3; ++k) {       // runtime loop: no cross-k hoisting
        // ---- stage k-plane: 2 rounds, both load batches issued up front ----
        {
            f32x4 vsA[4], vsB[4];
            SLD(vsA, 0, k); SLD(vsB, 1, k);
            SWR(vsA, 0);    SWR(vsB, 1);
        }
        __syncthreads();

        // ---- compute: 4 nf-quarters; acc[2] live; W frags re-read per quarter (L2) ----
#pragma unroll
        for (int Q = 0; Q < 4; ++Q) {
            f32x4 acc[2];
            acc[0] = (f32x4){0.f, 0.f, 0.f, 0.f};
            acc[1] = (f32x4){0.f, 0.f, 0.f, 0.f};
            half8 ah[2];
            ah[0] = *(const half8*)(WfH + WOFF(0));
#pragma unroll
            for (int s = 0; s < 8; ++s) {
                const int P = s & 1;
                if (s < 7) ah[P ^ 1] = *(const half8*)(WfH + WOFF(s + 1));
#pragma unroll
                for (int q2 = 0; q2 < 2; ++q2) {
                    const int nf = (Q << 1) + q2;
                    const half8 bh = *(const half8*)(&X[XI((nf << 4) + t16, (s << 5) + (g << 3))]);
                    acc[q2] = __builtin_amdgcn_mfma_f32_16x16x32_f16(ah[P], bh, acc[q2], 0, 0, 0);
                }
            }
            // dp += x_k * d_k for this quarter (x from LDS f16, C-frag layout)
#pragma unroll
            for (int q2 = 0; q2 < 2; ++q2) {
                const int nf = (Q << 1) + q2;
                const half4 xr = *(const half4*)(&X[XI((nf << 4) + t16, (wid << 4) + (g << 2))]);
#pragma unroll
                for (int r = 0; r < 4; ++r)
                    dp[nf][r] += (float)xr[r] * acc[q2][r];
            }
        }
        __syncthreads();   // plane free for next k's stage
    }

    // ---- epilogue: pack keys, top-2 per 32-n sub-window (4 of them), store ----
    const int cr = (wid << 4) + (g << 2);
#pragma unroll
    for (int r = 0; r < 4; ++r) {
#pragma unroll
        for (int w = 0; w < 4; ++w) {
            float d0 = dp[2 * w][r]     * 0.0625f;
            float d1 = dp[2 * w + 1][r] * 0.0625f;
            unsigned u0 = __float_as_uint(d0);
            unsigned k0 = (u0 & 0x80000000u) ? ~u0 : (u0 | 0x80000000u);
            unsigned u1 = __float_as_uint(d1);
            unsigned k1 = (u1 & 0x80000000u) ? ~u1 : (u1 | 0x80000000u);
            int nA = n0 + (w << 5) + t16;
            int nB = nA + 16;
            u64 A1 = ((u64)k0 << 32) | (unsigned)(~nA);
            u64 A2 = 0;
            u64 B1 = ((u64)k1 << 32) | (unsigned)(~nB);
            t2m(A1, A2, B1, 0);
#pragma unroll
            for (int m = 1; m <= 8; m <<= 1) {
                u64 C1 = shfl_xor_u64(A1, m);
                u64 C2 = shfl_xor_u64(A2, m);
                t2m(A1, A2, C1, C2);
            }
            if (t16 == 0) {
                int c = cr + r;
                btop[(size_t)((b << 8) + c) * 128 + (nw << 2) + w] = make_ulonglong2(A1, A2);
            }
        }
    }
}

// ---------- phase2: merge 128 windows, certify or exact-recompute, gather ----------
__global__ void phase2(const float* __restrict__ x, const float* __restrict__ W,
                       const ulonglong2* __restrict__ btop, float* __restrict__ out)
{
    const int bc = blockIdx.x;
    const int b = bc >> 8, c = bc & 255;
    const int lane = threadIdx.x;

    u64 A1 = 0, A2 = 0;
    u64 e1[2];
#pragma unroll
    for (int t = 0; t < 2; ++t) {
        ulonglong2 e = btop[(size_t)bc * 128 + t * 64 + lane];
        e1[t] = e.x;
        t2m(A1, A2, e.x, e.y);
    }
#pragma unroll
    for (int m = 1; m <= 32; m <<= 1) {
        u64 B1 = shfl_xor_u64(A1, m);
        u64 B2 = shfl_xor_u64(A2, m);
        t2m(A1, A2, B1, B2);
    }
    float v1 = unkey((unsigned)(A1 >> 32));
    float v2 = unkey((unsigned)(A2 >> 32));
    int winner = (int)(~(unsigned)A1) & (N_ - 1);

    if (!(v1 - v2 > TAU)) {
        float bv = -3.4e38f; int bi = 0x7fffffff;
#pragma unroll
        for (int t = 0; t < 2; ++t) {
            bool flag = unkey((unsigned)(e1[t] >> 32)) >= v1 - TAU;
            unsigned long long mask = __ballot(flag);
            while (mask) {
                int src = __builtin_ctzll(mask);
                mask &= mask - 1;
                int win = t * 64 + src;       // 32-n window
                for (int ch = 0; ch < 4; ++ch) {
                    int nbase = win * 32 + ch * 8;
                    float accv[8];
#pragma unroll
                    for (int m2 = 0; m2 < 8; ++m2) accv[m2] = 0.f;
                    float xc[3][8];
#pragma unroll
                    for (int k = 0; k < 3; ++k) {
                        const float* p = x + (((size_t)bc * 3 + k) << 12) + nbase;
#pragma unroll
                        for (int m2 = 0; m2 < 8; ++m2) xc[k][m2] = p[m2];
                    }
                    for (int q = 0; q < 4; ++q) {
                        int i = lane + (q << 6);
                        float wq = W[c * C_ + i];
#pragma unroll
                        for (int k = 0; k < 3; ++k) {
                            const float* p = x + ((((size_t)b * C_ + i) * 3 + k) << 12) + nbase;
#pragma unroll
                            for (int m2 = 0; m2 < 8; ++m2)
                                accv[m2] += wq * p[m2] * xc[k][m2];
                        }
                    }
#pragma unroll
                    for (int m2 = 0; m2 < 8; ++m2) {
#pragma unroll
                        for (int mm = 1; mm <= 32; mm <<= 1)
                            accv[m2] += __shfl_xor(accv[m2], mm);
                        int n = nbase + m2;
                        if (accv[m2] > bv || (accv[m2] == bv && n < bi)) { bv = accv[m2]; bi = n; }
                    }
                }
            }
        }
        winner = bi;
    }

    if (lane < 3)
        out[bc * 3 + lane] = x[(((size_t)bc * 3 + lane) << 12) + winner];
}

extern "C" void kernel_launch(void* const* d_in, const int* in_sizes, int n_in,
                              void* d_out, int out_size, void* d_ws, size_t ws_size,
                              hipStream_t stream) {
    const float* x = (const float*)d_in[0];
    const float* W = (const float*)d_in[1];
    float* out = (float*)d_out;

    _Float16*   WfH  = (_Float16*)d_ws;                      // 128 KB
    ulonglong2* btop = (ulonglong2*)((char*)d_ws + 262144);  // 8 MB: [bc][128] (K1,K2)

    prep_w<<<32, 256, 0, stream>>>(W, WfH);
    vn_main<<<B_ * 32, 1024, 0, stream>>>(x, WfH, btop);
    phase2<<<B_ * C_, 64, 0, stream>>>(x, W, btop, out);
}

// Round 16
// 120.538 us; speedup vs baseline: 1.6701x; 1.6701x over previous
//
#include <hip/hip_runtime.h>

typedef _Float16 half8 __attribute__((ext_vector_type(8)));
typedef _Float16 half4 __attribute__((ext_vector_type(4)));
typedef float    f32x4 __attribute__((ext_vector_type(4)));
typedef unsigned long long u64;

#define B_ 16
#define C_ 256
#define N_ 4096
#define TAU 0.025f

// f16 index into [k=3][n=64][i=256], 16B-chunk XOR swizzle.
// Reads (n=16nf+t16): 2-way. Writes (n=4nl+j, j fixed): 8 cols over 16 nl.
#define XI(k, n, i) ( (((k) * 64 + (n)) << 8) | ( ( ( ((i) >> 3) ^ ((((n) & 3) << 1) ^ (((n) >> 2) & 7)) ) & 31 ) << 3 ) | ((i) & 7) )

__device__ __forceinline__ u64 shfl_xor_u64(u64 v, int m) {
    unsigned lo = __shfl_xor((unsigned)v, m);
    unsigned hi = __shfl_xor((unsigned)(v >> 32), m);
    return ((u64)hi << 32) | lo;
}
// merge top-2 B into A (packed keys: higher = better; ~n low 32 gives first-index tie rule)
__device__ __forceinline__ void t2m(u64& A1, u64& A2, u64 B1, u64 B2) {
    bool aw = A1 > B1;
    u64 T1 = aw ? A1 : B1;
    u64 lv = aw ? B1 : A1;
    u64 wv = aw ? A2 : B2;
    A2 = lv > wv ? lv : wv;
    A1 = T1;
}
__device__ __forceinline__ float unkey(unsigned key) {
    unsigned u = (key & 0x80000000u) ? (key ^ 0x80000000u) : ~key;
    return __uint_as_float(u);
}

// ---------- prep: W' = 16*W -> f16 (hi only), A-fragment-major ----------
// f16 index: ((cb*8+s)*64 + l)*8 + j ;  c = cb*16+(l&15), i = s*32+(l>>4)*8+j
__global__ void prep_w(const float* __restrict__ W, _Float16* __restrict__ WfH) {
    int t = blockIdx.x * 256 + threadIdx.x;  // 0..8191
    int l = t & 63, g = t >> 6;
    int s = g & 7, cb = g >> 3;
    int c = cb * 16 + (l & 15);
    int i0 = s * 32 + (l >> 4) * 8;
    int base = ((cb * 8 + s) * 64 + l) * 8;
#pragma unroll
    for (int j = 0; j < 8; ++j)
        WfH[base + j] = (_Float16)(16.0f * W[c * C_ + i0 + j]);
}

// ---------- main: whole-K LDS (96 KB), 64-n window (256B segments), 1 barrier ----------
// grid: 16 b * 64 nw = 1024 blocks; 512 thr = 8 waves; wave cw owns c[32cw,32cw+32) x 64 n.
// dp is EPILOGUE-ONLY (no persistent arch state); acc[3][2][4] lives in AGPRs.
// launch_bounds(512,2): 2 waves/SIMD -> 256-reg budget -> spill impossible.
__global__ __launch_bounds__(512, 2) void vn_main(
    const float* __restrict__ x, const _Float16* __restrict__ WfH,
    ulonglong2* __restrict__ btop)
{
    __shared__ __align__(16) _Float16 X[3 * 64 * 256];   // 96 KB -> 1 block/CU

    const int tid  = threadIdx.x;
    const int lane = tid & 63;
    const int cw   = tid >> 6;          // 0..7 : 32-c slice
    const int b    = blockIdx.x >> 6;
    const int nw   = blockIdx.x & 63;
    const int n0   = nw << 6;           // 64-n window
    const int g    = lane >> 4;
    const int t16  = lane & 15;

    const float* xb = x + ((size_t)(b * 768) << 12);

    // stage: nl lane covers 4 n (f32x4); sg group covers 4 consecutive i, one k per round
    const int nl = tid & 15;
    const int sg = tid >> 4;            // 0..31

    f32x4 vsA[4], vsB[4];

#define SLD(VS, T) do { const int kk = (T) >> 1, ib = ((((T) & 1) << 7) + (sg << 2)); \
    _Pragma("unroll") for (int rr = 0; rr < 4; ++rr)                                  \
        VS[rr] = *(const f32x4*)(xb + ((size_t)((ib + rr) * 3 + kk) << 12) + n0 + (nl << 2)); \
    } while (0)

#define SWR(VS, T) do { const int kk = (T) >> 1, ib = ((((T) & 1) << 7) + (sg << 2)); \
    _Pragma("unroll") for (int j = 0; j < 4; ++j) {                                   \
        half4 hh; hh[0] = (_Float16)VS[0][j]; hh[1] = (_Float16)VS[1][j];             \
        hh[2] = (_Float16)VS[2][j]; hh[3] = (_Float16)VS[3][j];                       \
        *(half4*)(&X[XI(kk, (nl << 2) + j, ib)]) = hh; }                              \
    } while (0)

#define WOFF(CF, S) ((((((cw << 1) + (CF)) << 3) + (S)) * 64 + lane) << 3)

    half8 ah[2][2];
    // W slice-0 frags first (L2-resident, covered by stage)
    ah[0][0] = *(const half8*)(WfH + WOFF(0, 0));
    ah[0][1] = *(const half8*)(WfH + WOFF(1, 0));

    // ---- stage all 3 k-planes (6 rounds, 2-deep rolling, 256B segments) ----
    SLD(vsA, 0); SLD(vsB, 1);
    SWR(vsA, 0); SLD(vsA, 2);
    SWR(vsB, 1); SLD(vsB, 3);
    SWR(vsA, 2); SLD(vsA, 4);
    SWR(vsB, 3); SLD(vsB, 5);
    SWR(vsA, 4); SWR(vsB, 5);
    __syncthreads();     // the ONLY barrier: X read-only from here

    // ---- MFMA: d = W'@x_hi, single-pass f16, whole K resident ----
    f32x4 acc[3][2][4];  // [k][cf][nf] -> AGPR side
#pragma unroll
    for (int k = 0; k < 3; ++k)
#pragma unroll
        for (int cf = 0; cf < 2; ++cf)
#pragma unroll
            for (int nf = 0; nf < 4; ++nf) acc[k][cf][nf] = (f32x4){0.f, 0.f, 0.f, 0.f};

#pragma unroll
    for (int s = 0; s < 8; ++s) {
        const int P = s & 1;
        if (s < 7) {
            ah[P ^ 1][0] = *(const half8*)(WfH + WOFF(0, s + 1));
            ah[P ^ 1][1] = *(const half8*)(WfH + WOFF(1, s + 1));
        }
#pragma unroll
        for (int k = 0; k < 3; ++k)
#pragma unroll
            for (int nf = 0; nf < 4; ++nf) {
                const half8 bh = *(const half8*)(&X[XI(k, (nf << 4) + t16, (s << 5) + (g << 3))]);
#pragma unroll
                for (int cf = 0; cf < 2; ++cf)
                    acc[k][cf][nf] = __builtin_amdgcn_mfma_f32_16x16x32_f16(ah[P][cf], bh, acc[k][cf][nf], 0, 0, 0);
            }
    }

    // ---- epilogue: dp from LDS x, pack keys, top-2 per 32-n window (2 of them) ----
#pragma unroll
    for (int cf = 0; cf < 2; ++cf) {
        const int ci = (cw << 5) + (cf << 4) + (g << 2);
#pragma unroll
        for (int w = 0; w < 2; ++w) {
            half4 xA[3], xB[3];
#pragma unroll
            for (int k = 0; k < 3; ++k) {
                xA[k] = *(const half4*)(&X[XI(k, ((w << 1) << 4) + t16,       ci)]);
                xB[k] = *(const half4*)(&X[XI(k, (((w << 1) | 1) << 4) + t16, ci)]);
            }
#pragma unroll
            for (int r = 0; r < 4; ++r) {
                float dpA = 0.f, dpB = 0.f;
#pragma unroll
                for (int k = 0; k < 3; ++k) {
                    dpA += (float)xA[k][r] * acc[k][cf][(w << 1)][r];
                    dpB += (float)xB[k][r] * acc[k][cf][(w << 1) | 1][r];
                }
                dpA *= 0.0625f; dpB *= 0.0625f;
                unsigned uA = __float_as_uint(dpA);
                unsigned kA = (uA & 0x80000000u) ? ~uA : (uA | 0x80000000u);
                unsigned uB = __float_as_uint(dpB);
                unsigned kB = (uB & 0x80000000u) ? ~uB : (uB | 0x80000000u);
                int nA = n0 + (w << 5) + t16;
                int nB = nA + 16;
                u64 A1 = ((u64)kA << 32) | (unsigned)(~nA);
                u64 A2 = 0;
                u64 B1 = ((u64)kB << 32) | (unsigned)(~nB);
                t2m(A1, A2, B1, 0);
#pragma unroll
                for (int m = 1; m <= 8; m <<= 1) {
                    u64 C1 = shfl_xor_u64(A1, m);
                    u64 C2 = shfl_xor_u64(A2, m);
                    t2m(A1, A2, C1, C2);
                }
                if (t16 == 0) {
                    int c = ci + r;
                    btop[(size_t)((b << 8) + c) * 128 + (nw << 1) + w] = make_ulonglong2(A1, A2);
                }
            }
        }
    }
}

// ---------- phase2: merge 128 windows, certify or exact-recompute, gather ----------
__global__ void phase2(const float* __restrict__ x, const float* __restrict__ W,
                       const ulonglong2* __restrict__ btop, float* __restrict__ out)
{
    const int bc = blockIdx.x;
    const int b = bc >> 8, c = bc & 255;
    const int lane = threadIdx.x;

    u64 A1 = 0, A2 = 0;
    u64 e1[2];
#pragma unroll
    for (int t = 0; t < 2; ++t) {
        ulonglong2 e = btop[(size_t)bc * 128 + t * 64 + lane];
        e1[t] = e.x;
        t2m(A1, A2, e.x, e.y);
    }
#pragma unroll
    for (int m = 1; m <= 32; m <<= 1) {
        u64 B1 = shfl_xor_u64(A1, m);
        u64 B2 = shfl_xor_u64(A2, m);
        t2m(A1, A2, B1, B2);
    }
    float v1 = unkey((unsigned)(A1 >> 32));
    float v2 = unkey((unsigned)(A2 >> 32));
    int winner = (int)(~(unsigned)A1) & (N_ - 1);

    if (!(v1 - v2 > TAU)) {
        float bv = -3.4e38f; int bi = 0x7fffffff;
#pragma unroll
        for (int t = 0; t < 2; ++t) {
            bool flag = unkey((unsigned)(e1[t] >> 32)) >= v1 - TAU;
            unsigned long long mask = __ballot(flag);
            while (mask) {
                int src = __builtin_ctzll(mask);
                mask &= mask - 1;
                int win = t * 64 + src;       // 32-n window
                for (int ch = 0; ch < 4; ++ch) {
                    int nbase = win * 32 + ch * 8;
                    float accv[8];
#pragma unroll
                    for (int m2 = 0; m2 < 8; ++m2) accv[m2] = 0.f;
                    float xc[3][8];
#pragma unroll
                    for (int k = 0; k < 3; ++k) {
                        const float* p = x + (((size_t)bc * 3 + k) << 12) + nbase;
#pragma unroll
                        for (int m2 = 0; m2 < 8; ++m2) xc[k][m2] = p[m2];
                    }
                    for (int q = 0; q < 4; ++q) {
                        int i = lane + (q << 6);
                        float wq = W[c * C_ + i];
#pragma unroll
                        for (int k = 0; k < 3; ++k) {
                            const float* p = x + ((((size_t)b * C_ + i) * 3 + k) << 12) + nbase;
#pragma unroll
                            for (int m2 = 0; m2 < 8; ++m2)
                                accv[m2] += wq * p[m2] * xc[k][m2];
                        }
                    }
#pragma unroll
                    for (int m2 = 0; m2 < 8; ++m2) {
#pragma unroll
                        for (int mm = 1; mm <= 32; mm <<= 1)
                            accv[m2] += __shfl_xor(accv[m2], mm);
                        int n = nbase + m2;
                        if (accv[m2] > bv || (accv[m2] == bv && n < bi)) { bv = accv[m2]; bi = n; }
                    }
                }
            }
        }
        winner = bi;
    }

    if (lane < 3)
        out[bc * 3 + lane] = x[(((size_t)bc * 3 + lane) << 12) + winner];
}

extern "C" void kernel_launch(void* const* d_in, const int* in_sizes, int n_in,
                              void* d_out, int out_size, void* d_ws, size_t ws_size,
                              hipStream_t stream) {
    const float* x = (const float*)d_in[0];
    const float* W = (const float*)d_in[1];
    float* out = (float*)d_out;

    _Float16*   WfH  = (_Float16*)d_ws;                      // 128 KB
    ulonglong2* btop = (ulonglong2*)((char*)d_ws + 262144);  // 8 MB: [bc][128] (K1,K2)

    prep_w<<<32, 256, 0, stream>>>(W, WfH);
    vn_main<<<B_ * 64, 512, 0, stream>>>(x, WfH, btop);
    phase2<<<B_ * C_, 64, 0, stream>>>(x, W, btop, out);
}

// Round 17
// 119.705 us; speedup vs baseline: 1.6818x; 1.0070x over previous
//
#include <hip/hip_runtime.h>

typedef _Float16 half8 __attribute__((ext_vector_type(8)));
typedef _Float16 half4 __attribute__((ext_vector_type(4)));
typedef float    f32x4 __attribute__((ext_vector_type(4)));
typedef unsigned long long u64;

#define B_ 16
#define C_ 256
#define N_ 4096
#define TAU 0.025f

// f16 index into [k=3][n=64][i=256], 16B-chunk XOR swizzle.
// Reads (n=16nf+t16): 2-way. Writes (n=4nl+j, j fixed): 8 cols over 16 nl.
#define XI(k, n, i) ( (((k) * 64 + (n)) << 8) | ( ( ( ((i) >> 3) ^ ((((n) & 3) << 1) ^ (((n) >> 2) & 7)) ) & 31 ) << 3 ) | ((i) & 7) )

__device__ __forceinline__ u64 shfl_xor_u64(u64 v, int m) {
    unsigned lo = __shfl_xor((unsigned)v, m);
    unsigned hi = __shfl_xor((unsigned)(v >> 32), m);
    return ((u64)hi << 32) | lo;
}
// merge top-2 B into A (packed keys: higher = better; ~n low 32 gives first-index tie rule)
__device__ __forceinline__ void t2m(u64& A1, u64& A2, u64 B1, u64 B2) {
    bool aw = A1 > B1;
    u64 T1 = aw ? A1 : B1;
    u64 lv = aw ? B1 : A1;
    u64 wv = aw ? A2 : B2;
    A2 = lv > wv ? lv : wv;
    A1 = T1;
}
__device__ __forceinline__ float unkey(unsigned key) {
    unsigned u = (key & 0x80000000u) ? (key ^ 0x80000000u) : ~key;
    return __uint_as_float(u);
}

// ---------- prep: W' = 16*W -> f16 (hi only), A-fragment-major ----------
// f16 index: ((cb*8+s)*64 + l)*8 + j ;  c = cb*16+(l&15), i = s*32+(l>>4)*8+j
__global__ void prep_w(const float* __restrict__ W, _Float16* __restrict__ WfH) {
    int t = blockIdx.x * 256 + threadIdx.x;  // 0..8191
    int l = t & 63, g = t >> 6;
    int s = g & 7, cb = g >> 3;
    int c = cb * 16 + (l & 15);
    int i0 = s * 32 + (l >> 4) * 8;
    int base = ((cb * 8 + s) * 64 + l) * 8;
#pragma unroll
    for (int j = 0; j < 8; ++j)
        WfH[base + j] = (_Float16)(16.0f * W[c * C_ + i0 + j]);
}

// ---------- main: whole-K LDS (96 KB), 64-n window, 1 barrier, XCD-swizzled ----------
// grid: 1024 blocks; work id XCD-swizzled (m157 bijective form, 1024%8==0) so the
// 32 co-resident blocks of each XCD are CONSECUTIVE nw of the same b -> their
// 256B row-segments tile 8KB-contiguous spans at the DRAM/L2 level.
// Otherwise byte-identical to R16 (proven spill-free: VGPR 92, WRITE 8MB, absmax 0).
__global__ __launch_bounds__(512, 2) void vn_main(
    const float* __restrict__ x, const _Float16* __restrict__ WfH,
    ulonglong2* __restrict__ btop)
{
    __shared__ __align__(16) _Float16 X[3 * 64 * 256];   // 96 KB -> 1 block/CU

    const int wid2 = ((blockIdx.x & 7) << 7) + (blockIdx.x >> 3);   // XCD swizzle
    const int b    = wid2 >> 6;
    const int nw   = wid2 & 63;

    const int tid  = threadIdx.x;
    const int lane = tid & 63;
    const int cw   = tid >> 6;          // 0..7 : 32-c slice
    const int n0   = nw << 6;           // 64-n window
    const int g    = lane >> 4;
    const int t16  = lane & 15;

    const float* xb = x + ((size_t)(b * 768) << 12);

    // stage: nl lane covers 4 n (f32x4); sg group covers 4 consecutive i, one k per round
    const int nl = tid & 15;
    const int sg = tid >> 4;            // 0..31

    f32x4 vsA[4], vsB[4];

#define SLD(VS, T) do { const int kk = (T) >> 1, ib = ((((T) & 1) << 7) + (sg << 2)); \
    _Pragma("unroll") for (int rr = 0; rr < 4; ++rr)                                  \
        VS[rr] = *(const f32x4*)(xb + ((size_t)((ib + rr) * 3 + kk) << 12) + n0 + (nl << 2)); \
    } while (0)

#define SWR(VS, T) do { const int kk = (T) >> 1, ib = ((((T) & 1) << 7) + (sg << 2)); \
    _Pragma("unroll") for (int j = 0; j < 4; ++j) {                                   \
        half4 hh; hh[0] = (_Float16)VS[0][j]; hh[1] = (_Float16)VS[1][j];             \
        hh[2] = (_Float16)VS[2][j]; hh[3] = (_Float16)VS[3][j];                       \
        *(half4*)(&X[XI(kk, (nl << 2) + j, ib)]) = hh; }                              \
    } while (0)

#define WOFF(CF, S) ((((((cw << 1) + (CF)) << 3) + (S)) * 64 + lane) << 3)

    half8 ah[2][2];
    // W slice-0 frags first (L2-resident, covered by stage)
    ah[0][0] = *(const half8*)(WfH + WOFF(0, 0));
    ah[0][1] = *(const half8*)(WfH + WOFF(1, 0));

    // ---- stage all 3 k-planes (6 rounds, 2-deep rolling, 256B segments) ----
    SLD(vsA, 0); SLD(vsB, 1);
    SWR(vsA, 0); SLD(vsA, 2);
    SWR(vsB, 1); SLD(vsB, 3);
    SWR(vsA, 2); SLD(vsA, 4);
    SWR(vsB, 3); SLD(vsB, 5);
    SWR(vsA, 4); SWR(vsB, 5);
    __syncthreads();     // the ONLY barrier: X read-only from here

    // ---- MFMA: d = W'@x_hi, single-pass f16, whole K resident ----
    f32x4 acc[3][2][4];  // [k][cf][nf] -> AGPR side
#pragma unroll
    for (int k = 0; k < 3; ++k)
#pragma unroll
        for (int cf = 0; cf < 2; ++cf)
#pragma unroll
            for (int nf = 0; nf < 4; ++nf) acc[k][cf][nf] = (f32x4){0.f, 0.f, 0.f, 0.f};

#pragma unroll
    for (int s = 0; s < 8; ++s) {
        const int P = s & 1;
        if (s < 7) {
            ah[P ^ 1][0] = *(const half8*)(WfH + WOFF(0, s + 1));
            ah[P ^ 1][1] = *(const half8*)(WfH + WOFF(1, s + 1));
        }
#pragma unroll
        for (int k = 0; k < 3; ++k)
#pragma unroll
            for (int nf = 0; nf < 4; ++nf) {
                const half8 bh = *(const half8*)(&X[XI(k, (nf << 4) + t16, (s << 5) + (g << 3))]);
#pragma unroll
                for (int cf = 0; cf < 2; ++cf)
                    acc[k][cf][nf] = __builtin_amdgcn_mfma_f32_16x16x32_f16(ah[P][cf], bh, acc[k][cf][nf], 0, 0, 0);
            }
    }

    // ---- epilogue: dp from LDS x, pack keys, top-2 per 32-n window (2 of them) ----
#pragma unroll
    for (int cf = 0; cf < 2; ++cf) {
        const int ci = (cw << 5) + (cf << 4) + (g << 2);
#pragma unroll
        for (int w = 0; w < 2; ++w) {
            half4 xA[3], xB[3];
#pragma unroll
            for (int k = 0; k < 3; ++k) {
                xA[k] = *(const half4*)(&X[XI(k, ((w << 1) << 4) + t16,       ci)]);
                xB[k] = *(const half4*)(&X[XI(k, (((w << 1) | 1) << 4) + t16, ci)]);
            }
#pragma unroll
            for (int r = 0; r < 4; ++r) {
                float dpA = 0.f, dpB = 0.f;
#pragma unroll
                for (int k = 0; k < 3; ++k) {
                    dpA += (float)xA[k][r] * acc[k][cf][(w << 1)][r];
                    dpB += (float)xB[k][r] * acc[k][cf][(w << 1) | 1][r];
                }
                dpA *= 0.0625f; dpB *= 0.0625f;
                unsigned uA = __float_as_uint(dpA);
                unsigned kA = (uA & 0x80000000u) ? ~uA : (uA | 0x80000000u);
                unsigned uB = __float_as_uint(dpB);
                unsigned kB = (uB & 0x80000000u) ? ~uB : (uB | 0x80000000u);
                int nA = n0 + (w << 5) + t16;
                int nB = nA + 16;
                u64 A1 = ((u64)kA << 32) | (unsigned)(~nA);
                u64 A2 = 0;
                u64 B1 = ((u64)kB << 32) | (unsigned)(~nB);
                t2m(A1, A2, B1, 0);
#pragma unroll
                for (int m = 1; m <= 8; m <<= 1) {
                    u64 C1 = shfl_xor_u64(A1, m);
                    u64 C2 = shfl_xor_u64(A2, m);
                    t2m(A1, A2, C1, C2);
                }
                if (t16 == 0) {
                    int c = ci + r;
                    btop[(size_t)((b << 8) + c) * 128 + (nw << 1) + w] = make_ulonglong2(A1, A2);
                }
            }
        }
    }
}

// ---------- phase2: merge 128 windows, certify or exact-recompute, gather ----------
__global__ void phase2(const float* __restrict__ x, const float* __restrict__ W,
                       const ulonglong2* __restrict__ btop, float* __restrict__ out)
{
    const int bc = blockIdx.x;
    const int b = bc >> 8, c = bc & 255;
    const int lane = threadIdx.x;

    u64 A1 = 0, A2 = 0;
    u64 e1[2];
#pragma unroll
    for (int t = 0; t < 2; ++t) {
        ulonglong2 e = btop[(size_t)bc * 128 + t * 64 + lane];
        e1[t] = e.x;
        t2m(A1, A2, e.x, e.y);
    }
#pragma unroll
    for (int m = 1; m <= 32; m <<= 1) {
        u64 B1 = shfl_xor_u64(A1, m);
        u64 B2 = shfl_xor_u64(A2, m);
        t2m(A1, A2, B1, B2);
    }
    float v1 = unkey((unsigned)(A1 >> 32));
    float v2 = unkey((unsigned)(A2 >> 32));
    int winner = (int)(~(unsigned)A1) & (N_ - 1);

    if (!(v1 - v2 > TAU)) {
        float bv = -3.4e38f; int bi = 0x7fffffff;
#pragma unroll
        for (int t = 0; t < 2; ++t) {
            bool flag = unkey((unsigned)(e1[t] >> 32)) >= v1 - TAU;
            unsigned long long mask = __ballot(flag);
            while (mask) {
                int src = __builtin_ctzll(mask);
                mask &= mask - 1;
                int win = t * 64 + src;       // 32-n window
                for (int ch = 0; ch < 4; ++ch) {
                    int nbase = win * 32 + ch * 8;
                    float accv[8];
#pragma unroll
                    for (int m2 = 0; m2 < 8; ++m2) accv[m2] = 0.f;
                    float xc[3][8];
#pragma unroll
                    for (int k = 0; k < 3; ++k) {
                        const float* p = x + (((size_t)bc * 3 + k) << 12) + nbase;
#pragma unroll
                        for (int m2 = 0; m2 < 8; ++m2) xc[k][m2] = p[m2];
                    }
                    for (int q = 0; q < 4; ++q) {
                        int i = lane + (q << 6);
                        float wq = W[c * C_ + i];
#pragma unroll
                        for (int k = 0; k < 3; ++k) {
                            const float* p = x + ((((size_t)b * C_ + i) * 3 + k) << 12) + nbase;
#pragma unroll
                            for (int m2 = 0; m2 < 8; ++m2)
                                accv[m2] += wq * p[m2] * xc[k][m2];
                        }
                    }
#pragma unroll
                    for (int m2 = 0; m2 < 8; ++m2) {
#pragma unroll
                        for (int mm = 1; mm <= 32; mm <<= 1)
                            accv[m2] += __shfl_xor(accv[m2], mm);
                        int n = nbase + m2;
                        if (accv[m2] > bv || (accv[m2] == bv && n < bi)) { bv = accv[m2]; bi = n; }
                    }
                }
            }
        }
        winner = bi;
    }

    if (lane < 3)
        out[bc * 3 + lane] = x[(((size_t)bc * 3 + lane) << 12) + winner];
}

extern "C" void kernel_launch(void* const* d_in, const int* in_sizes, int n_in,
                              void* d_out, int out_size, void* d_ws, size_t ws_size,
                              hipStream_t stream) {
    const float* x = (const float*)d_in[0];
    const float* W = (const float*)d_in[1];
    float* out = (float*)d_out;

    _Float16*   WfH  = (_Float16*)d_ws;                      // 128 KB
    ulonglong2* btop = (ulonglong2*)((char*)d_ws + 262144);  // 8 MB: [bc][128] (K1,K2)

    prep_w<<<32, 256, 0, stream>>>(W, WfH);
    vn_main<<<B_ * 64, 512, 0, stream>>>(x, WfH, btop);
    phase2<<<B_ * C_, 64, 0, stream>>>(x, W, btop, out);
}